// Round 8
// baseline (1432.585 us; speedup 1.0000x reference)
//
#include <hip/hip_runtime.h>

// out = relu(x @ W1) @ W2
// x: [N,155] fp32, W1: [155,128] fp32, W2: [128,3] fp32, out: [N,3] fp32.
// v10: v9 (best: 834) with the barriers REMOVED from the tile loop.
//      Key observation: the x-tile is NOT shared across waves -- each wave
//      reads only its own 16 rows of xs. So staging is re-partitioned to
//      per-wave ownership (wave w stages f4 range [620w,620w+620) of each
//      tile -- still contiguous & coalesced), making the 16 waves fully
//      decoupled: no __syncthreads in the loop, no phase lockstep, DS
//      reads/writes and HBM loads from drifting waves mix continuously.
//      w1s/w2s are read-only after the single init barrier; xs regions are
//      wave-private; out stores are disjoint => race-free by construction.

#define N_TOTAL 1048576
#define IN_DIM 155
#define HIDDEN 128
#define BLOCK_THREADS 1024
#define TILE_ROWS 256
#define NTILES 16
#define ROWS_PER_BLOCK (TILE_ROWS * NTILES)  // 4096
#define XK 168                                // LDS k-stride (bf16): 336B rows, 16B aligned
#define TILE_ELEMS (TILE_ROWS * IN_DIM)       // 39680 floats
#define WAVE_F4 620                           // 16 rows * 155 floats / 4 per wave
#define F4_PER_LANE 10                        // ceil(620 / 64)

typedef __attribute__((ext_vector_type(4))) float fvec4;
typedef __attribute__((ext_vector_type(8))) short short8;   // 8 bf16 MFMA A/B frag
typedef __attribute__((ext_vector_type(4))) float floatx4;  // MFMA C/D frag

static __device__ __forceinline__ unsigned short f2bf(float f) {
  // round-to-nearest-even fp32 -> bf16 (inputs are finite normals)
  unsigned int u = __builtin_bit_cast(unsigned int, f);
  u += 0x7fffu + ((u >> 16) & 1u);
  return (unsigned short)(u >> 16);
}

// v += row_ror<N>(v): rotate within the 16-lane DPP row (VALU pipe, no DS op).
// ror 8,4,2,1 chain = full 16-lane sum in every lane. (validated v7-v9)
template <int CTRL>
static __device__ __forceinline__ float dpp_ror_add(float v) {
  const int m = __builtin_amdgcn_update_dpp(
      0, __builtin_bit_cast(int, v), CTRL, 0xf, 0xf, true);
  return v + __builtin_bit_cast(float, m);
}

__global__ __launch_bounds__(1024, 4) void fused_mlp_kernel(
    const float* __restrict__ x, const float* __restrict__ W1,
    const float* __restrict__ W2, float* __restrict__ out) {
  __shared__ __align__(16) unsigned short w1s[HIDDEN * XK];    // 43008 B, W1^T bf16
  __shared__ __align__(16) unsigned short xs[TILE_ROWS * XK];  // 86016 B, x tile bf16
  __shared__ __align__(16) float w2s[HIDDEN * 3];              // 1536 B

  const int tid = threadIdx.x;
  const int ln = tid & 15;
  const int quad = (tid >> 4) & 3;  // 16-lane group within the wave
  const int wave = tid >> 6;
  const int l = tid & 63;

  // ---- stage W1^T as bf16 into LDS ----
  for (int idx = tid; idx < IN_DIM * HIDDEN; idx += BLOCK_THREADS) {
    const int k = idx >> 7;
    const int n = idx & 127;
    w1s[n * XK + k] = f2bf(W1[idx]);
  }
  for (int idx = tid; idx < HIDDEN * 16; idx += BLOCK_THREADS) {  // zero k-pad 155..167
    const int n = idx >> 4;
    const int k = 152 + (idx & 15);
    if (k >= IN_DIM) w1s[n * XK + k] = 0;
  }
  // zero xs k-pad cols 155..167 (never overwritten by staging)
  for (int idx = tid; idx < TILE_ROWS * 13; idx += BLOCK_THREADS) {
    const int r = idx / 13;
    const int c = IN_DIM + (idx - r * 13);
    xs[r * XK + c] = 0;
  }
  // W2 into LDS (keeps VGPR count under the 4-wave/SIMD cap)
  for (int idx = tid; idx < HIDDEN * 3; idx += BLOCK_THREADS) w2s[idx] = W2[idx];
  __syncthreads();  // the ONLY barrier: w1s/w2s read-only below; xs wave-private

  const size_t block_e0 = (size_t)blockIdx.x * ROWS_PER_BLOCK * IN_DIM;
  const size_t brow0 = (size_t)blockIdx.x * ROWS_PER_BLOCK;

  // this wave's private slice: f4 range [wbase_f4, wbase_f4+620) of each tile
  // (= rows 16*wave .. 16*wave+15; 2480 floats = exactly 16 rows, row-aligned)
  const int wbase_f4 = wave * WAVE_F4;

  // epilogue routing: dst lane l (<48) pulls from src lane 16*(l/12) + (l%12)
  const int srcaddr = ((l / 12) * 16 + (l % 12)) << 2;

  // ---- prefetch this wave's slice of tile 0 (coalesced f4, contiguous) ----
  fvec4 pre[F4_PER_LANE];
  {
    const fvec4* src = reinterpret_cast<const fvec4*>(x + block_e0);
#pragma unroll
    for (int i = 0; i < F4_PER_LANE; ++i) {
      const int fl = l + i * 64;
      if (fl < WAVE_F4) pre[i] = src[wbase_f4 + fl];
    }
  }

  for (int t = 0; t < NTILES; ++t) {
    // ---- convert this wave's 16 rows -> xs (bf16, padded rows); re-issue
    //      each pre[i]'s next-tile load right after its last read ----
    const bool more = (t + 1 < NTILES);
    const fvec4* nsrc = reinterpret_cast<const fvec4*>(
        x + block_e0 + (size_t)(t + 1) * TILE_ELEMS);
#pragma unroll
    for (int i = 0; i < F4_PER_LANE; ++i) {
      const int fl = l + i * 64;
      if (fl < WAVE_F4) {
        const fvec4 v = pre[i];
        const int e0 = (wbase_f4 + fl) * 4;  // float idx within tile region
        const int r = e0 / IN_DIM;           // in [16*wave, 16*wave+16)
        const int c = e0 - r * IN_DIM;
#pragma unroll
        for (int j = 0; j < 4; ++j) {
          const int cc = c + j;
          const int wrap = (cc >= IN_DIM);
          xs[(r + wrap) * XK + (cc - wrap * IN_DIM)] = f2bf(v[j]);
        }
        if (more) pre[i] = nsrc[wbase_f4 + fl];
      }
    }
    // no barrier: within-wave ds_write -> ds_read ordering is handled by the
    // compiler's lgkmcnt waits; other waves never touch this region.

    // ---- layer 1: 16 rows (this wave's own), B-frags from LDS ----
    floatx4 acc[8];
#pragma unroll
    for (int c8 = 0; c8 < 8; ++c8) acc[c8] = (floatx4)0.f;
    const int rbase = wave * 16;
#pragma unroll
    for (int s = 0; s < 5; ++s) {
      const int kb = s * 32 + quad * 8;
      const short8 a = *reinterpret_cast<const short8*>(&xs[(rbase + ln) * XK + kb]);
#pragma unroll
      for (int t8 = 0; t8 < 8; ++t8) {
        const short8 b = *reinterpret_cast<const short8*>(&w1s[(t8 * 16 + ln) * XK + kb]);
        acc[t8] = __builtin_amdgcn_mfma_f32_16x16x32_bf16(a, b, acc[t8], 0, 0, 0);
      }
    }

    // ---- layer 2: relu + W2, reduce across 16-lane group ----
    // acc[t8][r] = h[row0 + quad*4 + r][16*t8 + ln]
    float part[4][3];
#pragma unroll
    for (int r = 0; r < 4; ++r)
#pragma unroll
      for (int c = 0; c < 3; ++c) part[r][c] = 0.f;
#pragma unroll
    for (int t8 = 0; t8 < 8; ++t8) {
      const float wa = w2s[(t8 * 16 + ln) * 3 + 0];
      const float wb = w2s[(t8 * 16 + ln) * 3 + 1];
      const float wc = w2s[(t8 * 16 + ln) * 3 + 2];
#pragma unroll
      for (int r = 0; r < 4; ++r) {
        const float hv = fmaxf(acc[t8][r], 0.f);
        part[r][0] = fmaf(hv, wa, part[r][0]);
        part[r][1] = fmaf(hv, wb, part[r][1]);
        part[r][2] = fmaf(hv, wc, part[r][2]);
      }
    }
    // full 16-lane reduce on DPP row_ror (VALU pipe; no DS ops, no conflicts)
#pragma unroll
    for (int r = 0; r < 4; ++r)
#pragma unroll
      for (int c = 0; c < 3; ++c) {
        float v = part[r][c];
        v = dpp_ror_add<0x128>(v);  // ror 8
        v = dpp_ror_add<0x124>(v);  // ror 4
        v = dpp_ror_add<0x122>(v);  // ror 2
        v = dpp_ror_add<0x121>(v);  // ror 1
        part[r][c] = v;
      }

    // ---- single coalesced 192B store per wave ----
    // lane j (j<12) of each 16-lane group selects part[j/3][j%3] (cndmask
    // tree), then dst lane l pulls from lane 16*(l/12) + (l%12).
    float v = part[0][0];
    v = (ln == 1) ? part[0][1] : v;
    v = (ln == 2) ? part[0][2] : v;
    v = (ln == 3) ? part[1][0] : v;
    v = (ln == 4) ? part[1][1] : v;
    v = (ln == 5) ? part[1][2] : v;
    v = (ln == 6) ? part[2][0] : v;
    v = (ln == 7) ? part[2][1] : v;
    v = (ln == 8) ? part[2][2] : v;
    v = (ln == 9) ? part[3][0] : v;
    v = (ln == 10) ? part[3][1] : v;
    v = (ln == 11) ? part[3][2] : v;
    const int vo = __builtin_amdgcn_ds_bpermute(srcaddr, __builtin_bit_cast(int, v));
    const size_t row0 = brow0 + (size_t)t * TILE_ROWS + wave * 16;
    if (l < 48) out[row0 * 3 + l] = __builtin_bit_cast(float, vo);
    // no end-of-loop barrier: this wave's next overwrite of its own region is
    // ordered behind its own reads by the in-order per-wave LDS pipeline.
  }
}

extern "C" void kernel_launch(void* const* d_in, const int* in_sizes, int n_in,
                              void* d_out, int out_size, void* d_ws, size_t ws_size,
                              hipStream_t stream) {
  const float* x = (const float*)d_in[0];
  const float* W1 = (const float*)d_in[1];
  const float* W2 = (const float*)d_in[2];
  float* out = (float*)d_out;
  fused_mlp_kernel<<<dim3(N_TOTAL / ROWS_PER_BLOCK), dim3(BLOCK_THREADS), 0, stream>>>(
      x, W1, W2, out);
}

// Round 9
// 835.948 us; speedup vs baseline: 1.7137x; 1.7137x over previous
//
#include <hip/hip_runtime.h>

// out = relu(x @ W1) @ W2
// x: [N,155] fp32, W1: [155,128] fp32, W2: [128,3] fp32, out: [N,3] fp32.
// v11: v9 (best: 834) with EXACTLY ONE change: the end-of-loop __syncthreads
//      (barrier-2) is replaced by a NON-DRAINING lds_barrier (lgkmcnt(0) +
//      raw s_barrier, no vmcnt(0)). The next tile's prefetch loads -- issued
//      mid-iteration, after barrier-1 -- now stay in flight across barrier-2
//      and are consumed in the next convert via per-register vmcnt waits,
//      removing the block-wide straggler drain stall each tile. Barrier-1
//      stays a plain __syncthreads (vmcnt is naturally 0 there; its drain is
//      free and it fences regalloc exactly as in v9 -- v10 showed what
//      happens when the compiler gets scheduling freedom: VGPR spill, 3x
//      FETCH). Everything else is byte-identical to v9.

#define N_TOTAL 1048576
#define IN_DIM 155
#define HIDDEN 128
#define BLOCK_THREADS 1024
#define TILE_ROWS 256
#define NTILES 16
#define ROWS_PER_BLOCK (TILE_ROWS * NTILES)  // 4096
#define XK 168                                // LDS k-stride (bf16): 336B rows, 16B aligned
#define TILE_ELEMS (TILE_ROWS * IN_DIM)       // 39680 floats
#define TILE_F4 (TILE_ELEMS / 4)              // 9920 float4s
#define F4_PER_THREAD 10                      // ceil(9920 / 1024)

typedef __attribute__((ext_vector_type(4))) float fvec4;
typedef __attribute__((ext_vector_type(8))) short short8;   // 8 bf16 MFMA A/B frag
typedef __attribute__((ext_vector_type(4))) float floatx4;  // MFMA C/D frag

static __device__ __forceinline__ unsigned short f2bf(float f) {
  // round-to-nearest-even fp32 -> bf16 (inputs are finite normals)
  unsigned int u = __builtin_bit_cast(unsigned int, f);
  u += 0x7fffu + ((u >> 16) & 1u);
  return (unsigned short)(u >> 16);
}

// LDS-visibility barrier WITHOUT vmcnt drain: prefetch loads stay in flight.
static __device__ __forceinline__ void lds_barrier() {
  __builtin_amdgcn_sched_barrier(0);
  asm volatile("s_waitcnt lgkmcnt(0)" ::: "memory");
  __builtin_amdgcn_s_barrier();
  __builtin_amdgcn_sched_barrier(0);
}

// v += row_ror<N>(v): rotate within the 16-lane DPP row (VALU pipe, no DS op).
// ror 8,4,2,1 chain = full 16-lane sum in every lane. (validated v7-v9)
template <int CTRL>
static __device__ __forceinline__ float dpp_ror_add(float v) {
  const int m = __builtin_amdgcn_update_dpp(
      0, __builtin_bit_cast(int, v), CTRL, 0xf, 0xf, true);
  return v + __builtin_bit_cast(float, m);
}

__global__ __launch_bounds__(1024, 4) void fused_mlp_kernel(
    const float* __restrict__ x, const float* __restrict__ W1,
    const float* __restrict__ W2, float* __restrict__ out) {
  __shared__ __align__(16) unsigned short w1s[HIDDEN * XK];    // 43008 B, W1^T bf16
  __shared__ __align__(16) unsigned short xs[TILE_ROWS * XK];  // 86016 B, x tile bf16
  __shared__ __align__(16) float w2s[HIDDEN * 3];              // 1536 B

  const int tid = threadIdx.x;
  const int ln = tid & 15;
  const int quad = (tid >> 4) & 3;  // 16-lane group within the wave
  const int wave = tid >> 6;
  const int l = tid & 63;

  // ---- stage W1^T as bf16 into LDS ----
  for (int idx = tid; idx < IN_DIM * HIDDEN; idx += BLOCK_THREADS) {
    const int k = idx >> 7;
    const int n = idx & 127;
    w1s[n * XK + k] = f2bf(W1[idx]);
  }
  for (int idx = tid; idx < HIDDEN * 16; idx += BLOCK_THREADS) {  // zero k-pad 155..167
    const int n = idx >> 4;
    const int k = 152 + (idx & 15);
    if (k >= IN_DIM) w1s[n * XK + k] = 0;
  }
  // zero xs k-pad cols 155..167 (never overwritten by staging)
  for (int idx = tid; idx < TILE_ROWS * 13; idx += BLOCK_THREADS) {
    const int r = idx / 13;
    const int c = IN_DIM + (idx - r * 13);
    xs[r * XK + c] = 0;
  }
  // W2 into LDS (keeps VGPR count under the 4-wave/SIMD cap)
  for (int idx = tid; idx < HIDDEN * 3; idx += BLOCK_THREADS) w2s[idx] = W2[idx];
  __syncthreads();

  const size_t block_e0 = (size_t)blockIdx.x * ROWS_PER_BLOCK * IN_DIM;
  const size_t brow0 = (size_t)blockIdx.x * ROWS_PER_BLOCK;

  // epilogue routing: dst lane l (<48) pulls from src lane 16*(l/12) + (l%12)
  const int srcaddr = ((l / 12) * 16 + (l % 12)) << 2;

  // ---- prefetch tile 0 (flat coalesced float4, 16B aligned) ----
  fvec4 pre[F4_PER_THREAD];
  {
    const fvec4* src = reinterpret_cast<const fvec4*>(x + block_e0);
#pragma unroll
    for (int i = 0; i < F4_PER_THREAD; ++i) {
      const int f = tid + i * BLOCK_THREADS;
      if (f < TILE_F4) pre[i] = src[f];
    }
  }

  for (int t = 0; t < NTILES; ++t) {
    // ---- convert prefetched tile -> xs (bf16, padded rows) ----
    // (per-register vmcnt waits gate each pre[i]; early regs convert while
    //  late loads are still in flight)
#pragma unroll
    for (int i = 0; i < F4_PER_THREAD; ++i) {
      const int f = tid + i * BLOCK_THREADS;
      if (f < TILE_F4) {
        const int e0 = f * 4;
        const int r = e0 / IN_DIM;
        const int c = e0 - r * IN_DIM;
#pragma unroll
        for (int j = 0; j < 4; ++j) {
          const int cc = c + j;
          const int wrap = (cc >= IN_DIM);
          xs[(r + wrap) * XK + (cc - wrap * IN_DIM)] = f2bf(pre[i][j]);
        }
      }
    }
    __syncthreads();  // barrier-1: xs visible; vmcnt naturally 0 here (all
                      // pre consumed) so the implicit drain costs nothing.

    // ---- issue next tile's loads (in flight through the REST OF THE TILE
    //      and across the non-draining barrier-2, consumed next convert) ----
    if (t + 1 < NTILES) {
      const fvec4* src = reinterpret_cast<const fvec4*>(
          x + block_e0 + (size_t)(t + 1) * TILE_ELEMS);
#pragma unroll
      for (int i = 0; i < F4_PER_THREAD; ++i) {
        const int f = tid + i * BLOCK_THREADS;
        if (f < TILE_F4) pre[i] = src[f];
      }
    }

    // ---- layer 1: 16 rows per wave, B-frags from LDS ----
    floatx4 acc[8];
#pragma unroll
    for (int c8 = 0; c8 < 8; ++c8) acc[c8] = (floatx4)0.f;
    const int rbase = wave * 16;
#pragma unroll
    for (int s = 0; s < 5; ++s) {
      const int kb = s * 32 + quad * 8;
      const short8 a = *reinterpret_cast<const short8*>(&xs[(rbase + ln) * XK + kb]);
#pragma unroll
      for (int t8 = 0; t8 < 8; ++t8) {
        const short8 b = *reinterpret_cast<const short8*>(&w1s[(t8 * 16 + ln) * XK + kb]);
        acc[t8] = __builtin_amdgcn_mfma_f32_16x16x32_bf16(a, b, acc[t8], 0, 0, 0);
      }
    }

    // ---- layer 2: relu + W2, reduce across 16-lane group ----
    // acc[t8][r] = h[row0 + quad*4 + r][16*t8 + ln]
    float part[4][3];
#pragma unroll
    for (int r = 0; r < 4; ++r)
#pragma unroll
      for (int c = 0; c < 3; ++c) part[r][c] = 0.f;
#pragma unroll
    for (int t8 = 0; t8 < 8; ++t8) {
      const float wa = w2s[(t8 * 16 + ln) * 3 + 0];
      const float wb = w2s[(t8 * 16 + ln) * 3 + 1];
      const float wc = w2s[(t8 * 16 + ln) * 3 + 2];
#pragma unroll
      for (int r = 0; r < 4; ++r) {
        const float hv = fmaxf(acc[t8][r], 0.f);
        part[r][0] = fmaf(hv, wa, part[r][0]);
        part[r][1] = fmaf(hv, wb, part[r][1]);
        part[r][2] = fmaf(hv, wc, part[r][2]);
      }
    }
    // full 16-lane reduce on DPP row_ror (VALU pipe; no DS ops, no conflicts)
#pragma unroll
    for (int r = 0; r < 4; ++r)
#pragma unroll
      for (int c = 0; c < 3; ++c) {
        float v = part[r][c];
        v = dpp_ror_add<0x128>(v);  // ror 8
        v = dpp_ror_add<0x124>(v);  // ror 4
        v = dpp_ror_add<0x122>(v);  // ror 2
        v = dpp_ror_add<0x121>(v);  // ror 1
        part[r][c] = v;
      }

    // ---- single coalesced 192B store per wave ----
    // lane j (j<12) of each 16-lane group selects part[j/3][j%3] (cndmask
    // tree), then dst lane l pulls from lane 16*(l/12) + (l%12).
    float v = part[0][0];
    v = (ln == 1) ? part[0][1] : v;
    v = (ln == 2) ? part[0][2] : v;
    v = (ln == 3) ? part[1][0] : v;
    v = (ln == 4) ? part[1][1] : v;
    v = (ln == 5) ? part[1][2] : v;
    v = (ln == 6) ? part[2][0] : v;
    v = (ln == 7) ? part[2][1] : v;
    v = (ln == 8) ? part[2][2] : v;
    v = (ln == 9) ? part[3][0] : v;
    v = (ln == 10) ? part[3][1] : v;
    v = (ln == 11) ? part[3][2] : v;
    const int vo = __builtin_amdgcn_ds_bpermute(srcaddr, __builtin_bit_cast(int, v));
    const size_t row0 = brow0 + (size_t)t * TILE_ROWS + wave * 16;
    if (l < 48) out[row0 * 3 + l] = __builtin_bit_cast(float, vo);

    lds_barrier();  // barrier-2: xs WAR protection only -- NO vmcnt drain;
                    // next tile's loads stay in flight into the next convert.
  }
}

extern "C" void kernel_launch(void* const* d_in, const int* in_sizes, int n_in,
                              void* d_out, int out_size, void* d_ws, size_t ws_size,
                              hipStream_t stream) {
  const float* x = (const float*)d_in[0];
  const float* W1 = (const float*)d_in[1];
  const float* W2 = (const float*)d_in[2];
  float* out = (float*)d_out;
  fused_mlp_kernel<<<dim3(N_TOTAL / ROWS_PER_BLOCK), dim3(BLOCK_THREADS), 0, stream>>>(
      x, W1, W2, out);
}